// Round 8
// baseline (75.971 us; speedup 1.0000x reference)
//
#include <hip/hip_runtime.h>
#include <math.h>

// ---------------------------------------------------------------------------
// RegressionLoss: chamfer(32x32 shape pairs of 256 3D pts) -> softmax vs
// normalized-embedding inner-product softmax -> mean |p_hat - p|.
// Inputs: d_in[0] = embeddings (64x512 f32), d_in[1] = xyz (64x256x3 f32).
// Output: d_out[0] single f32.
//
// R8: pairs_kernel == R3 verbatim (empirical best, 66.2us; R4/R5/R6/R7's
// structural variants all regressed -> loop is latency-bound, broadcast
// ds_read is cheap). finish_kernel shrunk to ONE WAVE (64 thr, 16 entries
// per thread, in-register width-32 shuffle softmax, no LDS, no barriers)
// to minimize the serial tail dispatch.
// Floor model: ~40us harness poison fill + ~16us restores/gaps + ~8-10us us.
// ---------------------------------------------------------------------------

typedef float f32x2 __attribute__((ext_vector_type(2)));

__device__ __forceinline__ float waveReduceSum64(float v) {
    #pragma unroll
    for (int m = 32; m > 0; m >>= 1) v += __shfl_xor(v, m, 64);
    return v;
}

// blocks [0,992): directional chamfer half. pb=b>>1 indexes strict upper
//   triangle (i<j) of 32; dir=b&1. Writes cdHalf[b] = mean_p min_q d2.
// blocks [992,1024): dot row i=b-992 -> dots[i*32+j], j=0..31.
__global__ __launch_bounds__(256) void pairs_kernel(const float* __restrict__ emb,
                                                    const float* __restrict__ xyz,
                                                    float* __restrict__ cdHalf,
                                                    float* __restrict__ dots) {
    const int t = threadIdx.x;
    const int b = blockIdx.x;

    __shared__ __align__(16) float S[3 * 256];   // inner shape SoA: x,y,z
    __shared__ float red[4];
    float* Sx = S;
    float* Sy = S + 256;
    float* Sz = S + 512;

    if (b < 992) {
        const int pb  = b >> 1;
        const int dir = b & 1;
        // strict-upper-triangle decode: row i has (31-i) entries
        int i = 0, rem = pb;
        while (rem >= (31 - i)) { rem -= (31 - i); ++i; }
        const int j = i + 1 + rem;

        const int outer = dir ? j : i;
        const int inner = dir ? i : j;

        const float* Po = xyz + (32 + outer) * 768;   // shapes = xyz[32:]
        const float* Pi = xyz + (32 + inner) * 768;

        // stage inner shape into LDS SoA
        const float ix = Pi[3*t], iy = Pi[3*t+1], iz = Pi[3*t+2];
        Sx[t] = ix; Sy[t] = iy; Sz[t] = iz;
        // my outer point
        const float px = Po[3*t], py = Po[3*t+1], pz = Po[3*t+2];
        __syncthreads();

        const f32x2 Px = {px, px}, Py = {py, py}, Pz = {pz, pz};
        float m0 = 3.4e38f;

        #pragma unroll 4
        for (int s = 0; s < 256; s += 4) {
            const float4 vx = *(const float4*)&Sx[s];   // broadcast b128
            const float4 vy = *(const float4*)&Sy[s];
            const float4 vz = *(const float4*)&Sz[s];
            {   // s, s+1
                const f32x2 bx = {vx.x, vx.y}, by = {vy.x, vy.y}, bz = {vz.x, vz.y};
                f32x2 dx = Px - bx, dy = Py - by, dz = Pz - bz;
                f32x2 d = dx*dx + dy*dy + dz*dz;
                m0 = fminf(m0, fminf(d.x, d.y));   // v_min3
            }
            {   // s+2, s+3
                const f32x2 bx = {vx.z, vx.w}, by = {vy.z, vy.w}, bz = {vz.z, vz.w};
                f32x2 dx = Px - bx, dy = Py - by, dz = Pz - bz;
                f32x2 d = dx*dx + dy*dy + dz*dz;
                m0 = fminf(m0, fminf(d.x, d.y));
            }
        }

        float v = waveReduceSum64(m0);
        if ((t & 63) == 0) red[t >> 6] = v;
        __syncthreads();
        if (t == 0)
            cdHalf[b] = (red[0] + red[1] + red[2] + red[3]) * (1.0f / 256.0f);
    } else {
        const int i = b - 992;    // sketch row 0..31
        float* rowi = S;          // 512 floats
        const float* Ei = emb + i * 512;
        rowi[t]       = Ei[t];
        rowi[t + 256] = Ei[t + 256];
        __syncthreads();

        const int w    = t >> 6;
        const int lane = t & 63;

        // norm^2 of sketch row i (redundant per wave, cheap)
        float ni = 0.0f;
        #pragma unroll
        for (int m = 0; m < 8; ++m) { float a = rowi[lane + 64*m]; ni += a*a; }
        ni = waveReduceSum64(ni);

        // 4 waves x 8 shape columns each
        for (int j = w; j < 32; j += 4) {
            const float* Ej = emb + (32 + j) * 512;
            float dot = 0.0f, nj = 0.0f;
            #pragma unroll
            for (int m = 0; m < 8; ++m) {
                float a  = rowi[lane + 64*m];
                float bv = Ej[lane + 64*m];
                dot += a * bv;
                nj  += bv * bv;
            }
            dot = waveReduceSum64(dot);
            nj  = waveReduceSum64(nj);
            if (lane == 0) dots[i * 32 + j] = dot * rsqrtf(ni * nj);
        }
    }
}

// 1 block x 64 threads (one wave): assemble cd, softmaxes, mean abs diff.
// Thread t handles entries idx = r*64 + t, r=0..15. Width-32 shuffle
// segments align with the 32-entry softmax rows. No LDS, no barriers.
__global__ __launch_bounds__(64) void finish_kernel(const float* __restrict__ cdHalf,
                                                    const float* __restrict__ dots,
                                                    float* __restrict__ out) {
    const int t = threadIdx.x;   // 0..63
    const float inv_denom = 1.0f / (2.0f * (0.997f / 3.0f) * (0.997f / 3.0f));

    float acc = 0.0f;

    #pragma unroll
    for (int r = 0; r < 16; ++r) {
        const int idx = r * 64 + t;      // idx = i*32 + j
        const int i = idx >> 5;
        const int j = idx & 31;

        float c;
        if (i == j) {
            c = 0.0f;                    // chamfer(self) == 0
        } else {
            const int a  = min(i, j), bb = max(i, j);
            const int pb = a * 31 - (a * (a - 1)) / 2 + (bb - a - 1);
            c = cdHalf[2 * pb] + cdHalf[2 * pb + 1];
        }
        float s = -(c * c) * inv_denom;
        float h = dots[idx];

        // softmax of s over the 32-wide row segment
        float m1 = s;
        #pragma unroll
        for (int k = 16; k > 0; k >>= 1) m1 = fmaxf(m1, __shfl_xor(m1, k, 32));
        float e1 = expf(s - m1);
        float sum1 = e1;
        #pragma unroll
        for (int k = 16; k > 0; k >>= 1) sum1 += __shfl_xor(sum1, k, 32);
        float p = e1 / sum1;

        // softmax of h over the row segment
        float m2 = h;
        #pragma unroll
        for (int k = 16; k > 0; k >>= 1) m2 = fmaxf(m2, __shfl_xor(m2, k, 32));
        float e2 = expf(h - m2);
        float sum2 = e2;
        #pragma unroll
        for (int k = 16; k > 0; k >>= 1) sum2 += __shfl_xor(sum2, k, 32);
        float ph = e2 / sum2;

        acc += fabsf(ph - p);
    }

    acc = waveReduceSum64(acc);
    if (t == 0) out[0] = acc * (1.0f / 1024.0f);
}

extern "C" void kernel_launch(void* const* d_in, const int* in_sizes, int n_in,
                              void* d_out, int out_size, void* d_ws, size_t ws_size,
                              hipStream_t stream) {
    const float* emb = (const float*)d_in[0];   // 64 x 512
    const float* xyz = (const float*)d_in[1];   // 64 x 256 x 3
    float* cdHalf = (float*)d_ws;               // 992 directional halves
    float* dots   = cdHalf + 1024;              // 32x32
    float* out    = (float*)d_out;

    hipLaunchKernelGGL(pairs_kernel, dim3(1024), dim3(256), 0, stream, emb, xyz, cdHalf, dots);
    hipLaunchKernelGGL(finish_kernel, dim3(1), dim3(64), 0, stream, cdHalf, dots, out);
}